// Round 5
// baseline (311.728 us; speedup 1.0000x reference)
//
#include <hip/hip_runtime.h>
#include <math.h>

#define DD 2048
#define HH 4096
#define NSTEPS 16
#define KK 4

// workspace float offsets
#define OFF_CAT    0        // h[4096], l[2048] (+pad to 6400)
#define OFF_GI_H   6400     // 12288
#define OFF_GH_H   18688    // 12288
#define OFF_GI_L   30976    // 6144
#define OFF_GH_L   37120    // 6144
#define OFF_DIR    43264    // 2048
#define OFF_RES    45312    // 2048 (res0 / generic res)
#define OFF_RESULT 47360    // 2048
#define OFF_SCAL   49408    // [0]cum [1]weight [3]mom [4]active [5]do_reset [6]raw_conv
                            // [8]conv_dot [9]halt_h_dot [10]p0 [11]p1
#define OFF_BAR    49440    // 2 x unsigned
#define OFF_XCAT   49472    // [q(2048), l(2048)]
#define OFF_RES2   53568    // 2048 (res1)

static __device__ __forceinline__ float sigf(float x) { return 1.0f / (1.0f + expf(-x)); }

static __device__ __forceinline__ float wred(float s) {
#pragma unroll
  for (int off = 32; off; off >>= 1) s += __shfl_down(s, off);
  return s;
}

// depth-8 dual-stream float4 row-dot: 16 loads in flight, 4 accumulators.
static __device__ __forceinline__ float dot8(const float4* __restrict__ Wr,
                                             const float4* __restrict__ x,
                                             int n4, int lane) {
  float a0 = 0.f, a1 = 0.f, a2 = 0.f, a3 = 0.f;
  for (int i = lane; i + 448 < n4; i += 512) {
    float4 w0 = Wr[i],       w1 = Wr[i + 64],  w2 = Wr[i + 128], w3 = Wr[i + 192];
    float4 w4 = Wr[i + 256], w5 = Wr[i + 320], w6 = Wr[i + 384], w7 = Wr[i + 448];
    float4 v0 = x[i],        v1 = x[i + 64],   v2 = x[i + 128],  v3 = x[i + 192];
    float4 v4 = x[i + 256],  v5 = x[i + 320],  v6 = x[i + 384],  v7 = x[i + 448];
    a0 = fmaf(w0.x, v0.x, a0); a0 = fmaf(w0.y, v0.y, a0); a0 = fmaf(w0.z, v0.z, a0); a0 = fmaf(w0.w, v0.w, a0);
    a1 = fmaf(w1.x, v1.x, a1); a1 = fmaf(w1.y, v1.y, a1); a1 = fmaf(w1.z, v1.z, a1); a1 = fmaf(w1.w, v1.w, a1);
    a2 = fmaf(w2.x, v2.x, a2); a2 = fmaf(w2.y, v2.y, a2); a2 = fmaf(w2.z, v2.z, a2); a2 = fmaf(w2.w, v2.w, a2);
    a3 = fmaf(w3.x, v3.x, a3); a3 = fmaf(w3.y, v3.y, a3); a3 = fmaf(w3.z, v3.z, a3); a3 = fmaf(w3.w, v3.w, a3);
    a0 = fmaf(w4.x, v4.x, a0); a0 = fmaf(w4.y, v4.y, a0); a0 = fmaf(w4.z, v4.z, a0); a0 = fmaf(w4.w, v4.w, a0);
    a1 = fmaf(w5.x, v5.x, a1); a1 = fmaf(w5.y, v5.y, a1); a1 = fmaf(w5.z, v5.z, a1); a1 = fmaf(w5.w, v5.w, a1);
    a2 = fmaf(w6.x, v6.x, a2); a2 = fmaf(w6.y, v6.y, a2); a2 = fmaf(w6.z, v6.z, a2); a2 = fmaf(w6.w, v6.w, a2);
    a3 = fmaf(w7.x, v7.x, a3); a3 = fmaf(w7.y, v7.y, a3); a3 = fmaf(w7.z, v7.z, a3); a3 = fmaf(w7.w, v7.w, a3);
  }
  return wred((a0 + a1) + (a2 + a3));
}

// software grid barrier (sense via generation counter); all blocks resident.
static __device__ __forceinline__ void gsync(unsigned* bar, unsigned* gen,
                                             unsigned nblk, unsigned& lg) {
  __syncthreads();
  if (threadIdx.x == 0) {
    __threadfence();
    unsigned arrived = __hip_atomic_fetch_add(bar, 1u, __ATOMIC_ACQ_REL,
                                              __HIP_MEMORY_SCOPE_AGENT);
    if (arrived == nblk - 1) {
      __hip_atomic_store(bar, 0u, __ATOMIC_RELAXED, __HIP_MEMORY_SCOPE_AGENT);
      __hip_atomic_fetch_add(gen, 1u, __ATOMIC_ACQ_REL, __HIP_MEMORY_SCOPE_AGENT);
    } else {
      long spins = 0;
      while (__hip_atomic_load(gen, __ATOMIC_ACQUIRE, __HIP_MEMORY_SCOPE_AGENT) == lg) {
        __builtin_amdgcn_s_sleep(2);
        if (++spins > (1L << 24)) break;   // safety: never hard-hang
      }
    }
    lg++;
    __threadfence();
  }
  __syncthreads();
}

#define GBAR gsync(bar, bar + 1, nblk, lg)

__global__ __launch_bounds__(256, 2) void k_all(
    const float* __restrict__ query,
    const float* __restrict__ h_wih, const float* __restrict__ h_whh,
    const float* __restrict__ h_bih, const float* __restrict__ h_bhh,
    const float* __restrict__ l_wih, const float* __restrict__ l_whh,
    const float* __restrict__ l_bih, const float* __restrict__ l_bhh,
    const float* __restrict__ dir_w, const float* __restrict__ dir_b,
    const float* __restrict__ conv_w, const float* __restrict__ conv_b,
    const float* __restrict__ out_w, const float* __restrict__ out_b,
    const float* __restrict__ halt_w, const float* __restrict__ halt_b,
    const float* __restrict__ reset_w, const float* __restrict__ reset_b,
    const float* __restrict__ init_w, const float* __restrict__ init_b,
    float* __restrict__ ws, float* __restrict__ out, unsigned nblk) {
  const int tid = threadIdx.x, lane = tid & 63, wib = tid >> 6;
  const int nw = (int)(gridDim.x << 2);
  const int wid = (int)((blockIdx.x << 2) | wib);
  const int gtid = (int)(blockIdx.x * 256 + tid);
  const int gsz = (int)(gridDim.x * 256);

  float* cat    = ws + OFF_CAT;
  float* gi_h   = ws + OFF_GI_H;
  float* gh_h   = ws + OFF_GH_H;
  float* gi_l   = ws + OFF_GI_L;
  float* gh_l   = ws + OFF_GH_L;
  float* dir    = ws + OFF_DIR;
  float* res    = ws + OFF_RES;
  float* res2   = ws + OFF_RES2;
  float* result = ws + OFF_RESULT;
  float* scal   = ws + OFF_SCAL;
  float* xcat   = ws + OFF_XCAT;
  unsigned* bar = (unsigned*)(ws + OFF_BAR);
  volatile float* vs = scal;
  unsigned lg = 0;

  __shared__ float l0s[DD];
  __shared__ float l1s[DD];

  const float4* q4 = (const float4*)query;

  // ---- P0: gi_h = h_wih[:, :2048] @ q + bih (h=0, l=0 at step 0); seed xcat[q]
  for (int r = wid; r < 3 * HH; r += nw) {
    float s = dot8((const float4*)h_wih + (size_t)r * 1024, q4, 512, lane);
    if (lane == 0) gi_h[r] = s + h_bih[r];
  }
  for (int i = gtid; i < DD; i += gsz) xcat[i] = query[i];
  GBAR;

  // ---- P1: h-combine cooperative (gh == bhh since h was 0)
  for (int i = gtid; i < HH; i += gsz) {
    float r = sigf(gi_h[i] + h_bhh[i]);
    float z = sigf(gi_h[HH + i] + h_bhh[HH + i]);
    float n = tanhf(gi_h[2 * HH + i] + r * h_bhh[2 * HH + i]);
    cat[i] = (1.0f - z) * n;
  }
  GBAR;

  // ---- P2: dir = tanh(dir_w @ h + b); conv dot -> scal[8]; halt-h dot -> scal[9]
  for (int r = wid; r < DD; r += nw) {
    float s = dot8((const float4*)dir_w + (size_t)r * 1024, (const float4*)cat, 1024, lane);
    if (lane == 0) dir[r] = tanhf(s + dir_b[r]);
  }
  if (wid == 0) {
    float s = dot8((const float4*)conv_w, (const float4*)cat, 1024, lane);
    if (lane == 0) scal[8] = s;
  }
  if (wid == 1) {
    float s = dot8((const float4*)halt_w, (const float4*)cat, 1024, lane);
    if (lane == 0) scal[9] = s;
  }
  GBAR;

  // ---- P3: gi_l = l_wih @ dir + bih
  for (int r = wid; r < 3 * DD; r += nw) {
    float s = dot8((const float4*)l_wih + (size_t)r * 512, (const float4*)dir, 512, lane);
    if (lane == 0) gi_l[r] = s + l_bih[r];
  }
  GBAR;

  // ---- P4: per-block redundant l0-combine (gh==l_bhh) -> LDS; block0 scalars;
  //          task pool: gh_l (6144 rows) || res0 (2048 rows)
  for (int i = tid; i < DD; i += 256) {
    float r = sigf(gi_l[i] + l_bhh[i]);
    float z = sigf(gi_l[DD + i] + l_bhh[DD + i]);
    float n = tanhf(gi_l[2 * DD + i] + r * l_bhh[2 * DD + i]);
    l0s[i] = (1.0f - z) * n;
  }
  __syncthreads();
  if (blockIdx.x == 0) {
    if (wib == 0) {
      float s = 0.f;
      for (int i = lane; i < DD; i += 64) s += halt_w[HH + i] * l0s[i];
      s = wred(s);
      if (lane == 0) {
        float raw = sigf(scal[8] + conv_b[0]);
        scal[6] = raw;
        scal[3] = 0.1f * raw;                 // mom
        float halt = sigf(scal[9] + s + halt_b[0]);
        float p = fminf(halt, 1.0f);          // cum was 0
        scal[10] = p;                         // p0
        scal[1] = p; scal[0] = p;             // weight, cum
        scal[4] = (p > 0.95f) ? 0.0f : 1.0f;  // active
        scal[5] = 0.0f;
      }
    }
    for (int i = tid; i < DD; i += 256) { cat[HH + i] = l0s[i]; xcat[DD + i] = l0s[i]; }
  }
  for (int t = wid; t < 8192; t += nw) {
    if (t < 6144) {
      float s = dot8((const float4*)l_whh + (size_t)t * 512, (const float4*)l0s, 512, lane);
      if (lane == 0) gh_l[t] = s + l_bhh[t];
    } else {
      int r = t - 6144;
      float s = dot8((const float4*)out_w + (size_t)r * 512, (const float4*)l0s, 512, lane);
      if (lane == 0) res[r] = tanhf(s + out_b[r]);
    }
  }
  GBAR;

  // ---- P5: step 1 (h, dir, gi_l unchanged): l1-combine redundant -> LDS; scalars; res1
  bool act0 = (vs[4] != 0.0f);
  if (act0) {
    for (int i = tid; i < DD; i += 256) {
      float r = sigf(gi_l[i] + gh_l[i]);
      float z = sigf(gi_l[DD + i] + gh_l[DD + i]);
      float n = tanhf(gi_l[2 * DD + i] + r * gh_l[2 * DD + i]);
      l1s[i] = (1.0f - z) * n + z * l0s[i];
    }
    __syncthreads();
    if (blockIdx.x == 0) {
      if (wib == 0) {
        float s = 0.f;
        for (int i = lane; i < DD; i += 64) s += halt_w[HH + i] * l1s[i];
        s = wred(s);
        if (lane == 0) {
          scal[3] = 0.9f * scal[3] + 0.1f * scal[6];   // raw unchanged (h unchanged)
          float halt = sigf(scal[9] + s + halt_b[0]);
          float cum = scal[0];
          float p = fminf(halt, 1.0f - cum);
          scal[11] = p;                                 // p1
          scal[1] += p; cum += p; scal[0] = cum;
          scal[4] = (cum > 0.95f) ? 0.0f : 1.0f;
        }
      }
      for (int i = tid; i < DD; i += 256) { cat[HH + i] = l1s[i]; xcat[DD + i] = l1s[i]; }
    }
    for (int r = wid; r < DD; r += nw) {
      float s = dot8((const float4*)out_w + (size_t)r * 512, (const float4*)l1s, 512, lane);
      if (lane == 0) res2[r] = tanhf(s + out_b[r]);
    }
  } else {
    if (blockIdx.x == 0 && tid == 0) scal[11] = 0.0f;
  }
  GBAR;

  // ---- rare path: still active after step 1 -> generic steps 2..15
  bool rare = (vs[4] != 0.0f);
  if (rare) {
    float p0v = vs[10], p1v = vs[11];
    for (int i = gtid; i < DD; i += gsz) result[i] = p0v * res[i] + p1v * res2[i];
    GBAR;
    for (int step = 2; step < NSTEPS; ++step) {
      if (vs[4] == 0.0f) break;
      const bool hstep = ((step & 3) == 0);
      if (hstep) {
        for (int r = wid; r < 6 * HH; r += nw) {
          if (r < 3 * HH) {
            float s = dot8((const float4*)h_wih + (size_t)r * 1024,
                           (const float4*)xcat, 1024, lane);
            if (lane == 0) gi_h[r] = s + h_bih[r];
          } else {
            int rr = r - 3 * HH;
            float s = dot8((const float4*)h_whh + (size_t)rr * 1024,
                           (const float4*)cat, 1024, lane);
            if (lane == 0) gh_h[rr] = s + h_bhh[rr];
          }
        }
        GBAR;
        for (int i = gtid; i < HH; i += gsz) {
          float rr = sigf(gi_h[i] + gh_h[i]);
          float z = sigf(gi_h[HH + i] + gh_h[HH + i]);
          float nn = tanhf(gi_h[2 * HH + i] + rr * gh_h[2 * HH + i]);
          cat[i] = (1.0f - z) * nn + z * cat[i];
        }
        GBAR;
        for (int r = wid; r < DD; r += nw) {
          float s = dot8((const float4*)dir_w + (size_t)r * 1024,
                         (const float4*)cat, 1024, lane);
          if (lane == 0) dir[r] = tanhf(s + dir_b[r]);
        }
        GBAR;
      }
      {
        const int tot = hstep ? 12288 : 6144;   // gi_l only when dir changed
        for (int r = wid; r < tot; r += nw) {
          if (r < 6144) {
            float s = dot8((const float4*)l_whh + (size_t)r * 512,
                           (const float4*)(cat + HH), 512, lane);
            if (lane == 0) gh_l[r] = s + l_bhh[r];
          } else {
            int rr = r - 6144;
            float s = dot8((const float4*)l_wih + (size_t)rr * 512,
                           (const float4*)dir, 512, lane);
            if (lane == 0) gi_l[rr] = s + l_bih[rr];
          }
        }
      }
      GBAR;
      for (int i = gtid; i < DD; i += gsz) {
        float rr = sigf(gi_l[i] + gh_l[i]);
        float z = sigf(gi_l[DD + i] + gh_l[DD + i]);
        float nn = tanhf(gi_l[2 * DD + i] + rr * gh_l[2 * DD + i]);
        float lv = (1.0f - z) * nn + z * cat[HH + i];
        cat[HH + i] = lv;
        xcat[DD + i] = lv;
      }
      GBAR;
      for (int r = wid; r < DD; r += nw) {
        float s = dot8((const float4*)out_w + (size_t)r * 512,
                       (const float4*)(cat + HH), 512, lane);
        if (lane == 0) res[r] = tanhf(s + out_b[r]);
      }
      GBAR;
      if (blockIdx.x == 0) {
        __shared__ float red[4];
        __shared__ float s_p;
        float s = 0.f;
        if (wib == 0) {
          if (hstep) {
            for (int i = lane; i < HH; i += 64) s += conv_w[i] * cat[i];
            s = wred(s);
            if (lane == 0) red[0] = s;
          }
        } else if (wib == 1) {
          for (int i = lane; i < HH + DD; i += 64) s += halt_w[i] * cat[i];
          s = wred(s);
          if (lane == 0) red[1] = s;
        } else if (wib == 2) {
          for (int i = lane; i < HH + DD; i += 64) s += reset_w[i] * cat[i];
          s = wred(s);
          if (lane == 0) red[2] = s;
        }
        __syncthreads();
        if (tid == 0) {
          float raw = hstep ? sigf(red[0] + conv_b[0]) : scal[6];
          if (hstep) scal[6] = raw;
          float mom = 0.9f * scal[3] + 0.1f * raw;
          scal[3] = mom;
          float halt = sigf(red[1] + halt_b[0]);
          float cum = scal[0];
          float p = fminf(halt, 1.0f - cum);
          scal[1] += p;
          cum += p;
          scal[0] = cum;
          bool brk = cum > 0.95f;
          float rdot = red[2] + reset_w[HH + DD] * mom + reset_b[0];
          scal[5] = (!brk && (sigf(rdot) > 0.7f) && (step > KK)) ? 1.0f : 0.0f;
          scal[4] = brk ? 0.0f : 1.0f;
          s_p = p;
        }
        __syncthreads();
        float p = s_p;
        for (int i = tid; i < DD; i += 256) result[i] += p * res[i];
        __threadfence();
      }
      GBAR;
      if (step > KK && vs[5] != 0.0f) {
        for (int r = wid; r < DD; r += nw) {
          float s = dot8((const float4*)init_w + (size_t)r * 1024,
                         (const float4*)cat, 1024, lane);
          if (lane == 0) {
            float lv = tanhf(s + init_b[r]);
            cat[HH + r] = lv;
            xcat[DD + r] = lv;
          }
        }
        GBAR;
      }
    }
  }

  // ---- final output
  float wgt = fmaxf(vs[1], 1e-8f);
  if (rare) {
    for (int i = gtid; i < DD; i += gsz) out[i] = result[i] / wgt;
  } else {
    float p0v = vs[10], p1v = vs[11];
    for (int i = gtid; i < DD; i += gsz) out[i] = (p0v * res[i] + p1v * res2[i]) / wgt;
  }
}

extern "C" void kernel_launch(void* const* d_in, const int* in_sizes, int n_in,
                              void* d_out, int out_size, void* d_ws, size_t ws_size,
                              hipStream_t stream) {
  const float* query   = (const float*)d_in[0];
  const float* h_wih   = (const float*)d_in[1];
  const float* h_whh   = (const float*)d_in[2];
  const float* h_bih   = (const float*)d_in[3];
  const float* h_bhh   = (const float*)d_in[4];
  const float* l_wih   = (const float*)d_in[5];
  const float* l_whh   = (const float*)d_in[6];
  const float* l_bih   = (const float*)d_in[7];
  const float* l_bhh   = (const float*)d_in[8];
  const float* dir_w   = (const float*)d_in[9];
  const float* dir_b   = (const float*)d_in[10];
  const float* conv_w  = (const float*)d_in[11];
  const float* conv_b  = (const float*)d_in[12];
  const float* out_w   = (const float*)d_in[13];
  const float* out_b   = (const float*)d_in[14];
  const float* halt_w  = (const float*)d_in[15];
  const float* halt_b  = (const float*)d_in[16];
  const float* reset_w = (const float*)d_in[17];
  const float* reset_b = (const float*)d_in[18];
  const float* init_w  = (const float*)d_in[19];
  const float* init_b  = (const float*)d_in[20];

  float* ws = (float*)d_ws;
  float* out = (float*)d_out;

  // zero the grid-barrier state (graph-legal)
  hipMemsetAsync((char*)d_ws + OFF_BAR * 4, 0, 8, stream);

  int maxb = 0;
  if (hipOccupancyMaxActiveBlocksPerMultiprocessor(&maxb, k_all, 256, 0) != hipSuccess)
    maxb = 1;
  unsigned nblk = (maxb >= 2) ? 512u : 256u;   // guaranteed co-resident

  k_all<<<nblk, 256, 0, stream>>>(query,
                                  h_wih, h_whh, h_bih, h_bhh,
                                  l_wih, l_whh, l_bih, l_bhh,
                                  dir_w, dir_b, conv_w, conv_b,
                                  out_w, out_b, halt_w, halt_b,
                                  reset_w, reset_b, init_w, init_b,
                                  ws, out, nblk);
}